// Round 1
// 515.064 us; speedup vs baseline: 2.3157x; 2.3157x over previous
//
#include <hip/hip_runtime.h>

// Problem: B,C,H,W = 16,256,32,32; K=16384. N = 16384 rows.
// R11: (1) k2 single-plane bf16 (drop lo planes: dot-err sigma ~5e-7 << MARGIN;
//          ns1 per-row constant dropped from approx score -> no 1.5e-5 grid rounding),
//          MFMA count /3, double-buffered Bs with issue-early pipeline (1 barrier/step).
//      (2) k5 rebuilt: transpose-tile coalesced out-writes (was stride-4KB scalar),
//          per-block partials instead of 32768 same-address global atomicAdds.
//      (3) bf16 converts fused into k1a / k_rownorm; k_split x2 + memset deleted.
#define KCODES 16384
#define NPOS   16384
#define CAP    64      // r10: CAP=16 overflowed on ~4 rows -> serial fallback tail
#define MARGIN 1e-4f   // ~100x the single-plane bf16 dot error (sigma ~1e-6 on d)

// ws float offsets
#define OFF_XT    0           // [N][256] fp32 packed x ("flat")
#define OFF_XHP   4194304     // bf16 plane xh [N][256]
#define OFF_PART  6291456     // [4096][2] k5 per-block {mask,err} partials (old XLP slot)
#define OFF_WHP   8388608     // bf16 plane wh [K][256]
#define OFF_WN    12582912    // [K]  |w|^2 (np-pairwise exact)
#define OFF_NS1   12599296    // [N] -|f|^2
#define OFF_IDX   12615680    // [N] final argmax (int)
#define OFF_CAND  12632064    // u16 [N][64] candidate codes
#define OFF_CCNT  13156352    // [N] candidate counts (int)

#define OUT_LOSS  4194304
#define OUT_IND   4194305

#define AS1 __attribute__((address_space(1)))
#define AS3 __attribute__((address_space(3)))

typedef short bf16x8 __attribute__((ext_vector_type(8)));   // 8 bf16 = 4 VGPRs
typedef float f32x4  __attribute__((ext_vector_type(4)));

__device__ inline unsigned short bf16rn(float f) {
    unsigned u = __float_as_uint(f);
    return (unsigned short)((u + 0x7FFFu + ((u >> 16) & 1u)) >> 16);
}
__device__ inline float bf2f(unsigned short h) {
    return __uint_as_float(((unsigned)h) << 16);
}
__device__ inline unsigned monof(float f) {   // monotone float->uint key
    unsigned u = __float_as_uint(f);
    return (u & 0x80000000u) ? ~u : (u | 0x80000000u);
}
__device__ inline float unmonof(unsigned k) {
    unsigned u = (k & 0x80000000u) ? (k & 0x7fffffffu) : ~k;
    return __uint_as_float(u);
}

// ---------- K1a: pack x (B,C,HW) -> xt[N][256] fp32 + xh bf16, LDS transpose ----
__global__ void k1a_pack_x(const float* __restrict__ x, float* __restrict__ xt,
                           unsigned short* __restrict__ xhp)
{
    __shared__ float t[32][33];
    const int p0 = blockIdx.x * 32, c0 = blockIdx.y * 32, b = blockIdx.z;
    const int tx = threadIdx.x, ty = threadIdx.y;   // 32 x 8
#pragma unroll
    for (int i = 0; i < 4; ++i) {
        int cl = ty + i * 8;
        t[cl][tx] = x[(b * 256 + c0 + cl) * 1024 + p0 + tx];
    }
    __syncthreads();
#pragma unroll
    for (int i = 0; i < 4; ++i) {
        int pl = ty + i * 8;
        float v = t[tx][pl];
        int o = (b * 1024 + p0 + pl) * 256 + c0 + tx;
        xt[o] = v;
        xhp[o] = bf16rn(v);
    }
}

// ---------- Krn: numpy-pairwise fp32 sum of squares per 256-elem row ----------
// (optionally also emits the bf16 hi plane while the data is in registers)
__global__ void k_rownorm(const float4* __restrict__ src4, float* __restrict__ out,
                          float sign, ushort4* __restrict__ hp)
{
    __shared__ float4 rows[32 * 64];
    const int tid = threadIdx.x;
    const int r0 = blockIdx.x * 32;
#pragma unroll
    for (int i = 0; i < 8; ++i) {
        const float4 v = src4[r0 * 64 + tid + 256 * i];
        rows[tid + 256 * i] = v;
        if (hp) {
            ushort4 h;
            h.x = bf16rn(v.x); h.y = bf16rn(v.y);
            h.z = bf16rn(v.z); h.w = bf16rn(v.w);
            hp[r0 * 64 + tid + 256 * i] = h;
        }
    }
    __syncthreads();
    const int rl = tid >> 3, j = tid & 7;
    const float* qp = (const float*)&rows[rl * 64];
    float h[2];
#pragma unroll
    for (int half = 0; half < 2; ++half) {
        const float* p = qp + half * 128;
        float x = p[j];
        float r = __fmul_rn(x, x);
#pragma unroll
        for (int i = 1; i < 16; ++i) {
            float y = p[8 * i + j];
            r = __fadd_rn(r, __fmul_rn(y, y));
        }
        float t = __fadd_rn(r, __shfl_xor(r, 1));
        t = __fadd_rn(t, __shfl_xor(t, 2));
        t = __fadd_rn(t, __shfl_xor(t, 4));
        h[half] = t;
    }
    if (j == 0) out[r0 + rl] = sign * __fadd_rn(h[0], h[1]);
}

// ---------- K2: single-plane bf16 MFMA + approx-d argmax candidate collection --
// d_approx = 2*(xh.wh) - |w|^2 ; the per-row constant -|f|^2 is omitted (argmax-
// invariant, and removing it kills the fp32 grid-rounding of adding -256).
__global__ __launch_bounds__(256, 2) void k2_mfma(
    const unsigned short* __restrict__ xhp, const unsigned short* __restrict__ whp,
    const float* __restrict__ wn,
    unsigned short* __restrict__ candk, int* __restrict__ candc)
{
    __shared__ __align__(16) unsigned short As[8192];      // 16KB: slot16 = cc*32 + row
    __shared__ __align__(16) unsigned short Bs[2][8192];   // 2x16KB: slot16 = code*4 + q'
    __shared__ unsigned rowmaxU[32];
    __shared__ int ccnt[32];
    __shared__ unsigned short ck[32][CAP];                 // 4 KB

    const int tid  = threadIdx.x;
    const int lane = tid & 63;
    const int w    = tid >> 6;     // wave 0..3 -> code sub-range
    const int q    = lane >> 4;    // k-chunk quad
    const int nn   = lane & 15;    // A-row / B-col / D-col position
    const int rowBase = blockIdx.x * 32;

    // stage A once: 1024 slots of 16B
#pragma unroll
    for (int i = 0; i < 4; ++i) {
        const int slot = i * 256 + tid;
        const int cc = slot >> 5, row = slot & 31;
        const unsigned short* src = xhp + (rowBase + row) * 256 + cc * 8;
        __builtin_amdgcn_global_load_lds((const AS1 void*)src,
                                         (AS3 void*)((char*)&As[0] + slot * 16), 16, 0, 0);
    }
    // stage B buf0 for step 0 (ch=0, cs=0)
#pragma unroll
    for (int i = 0; i < 4; ++i) {
        const int slot = i * 256 + tid;
        const int code = slot >> 2;
        const int qq = (slot & 3) ^ ((code >> 1) & 3);     // bank swizzle
        const unsigned short* src = whp + code * 256 + qq * 8;
        __builtin_amdgcn_global_load_lds((const AS1 void*)src,
            (AS3 void*)((char*)&Bs[0][0] + slot * 16), 16, 0, 0);
    }
    if (tid < 32) { rowmaxU[tid] = 0u; ccnt[tid] = 0; }
    __syncthreads();           // drains vmcnt: As + Bs[0] ready

    int buf = 0;
    for (int ch = 0; ch < 64; ++ch) {
        const int kb = ch * 256;
        f32x4 acc[2][4];
#pragma unroll
        for (int rt = 0; rt < 2; ++rt)
#pragma unroll
            for (int ct = 0; ct < 4; ++ct) acc[rt][ct] = (f32x4){0.f, 0.f, 0.f, 0.f};

        for (int cs = 0; cs < 8; ++cs) {
            // issue next step's staging into the other buffer (issue-early)
            const int stepNext = ch * 8 + cs + 1;
            if (stepNext < 512) {
                const int nch = stepNext >> 3, ncs = stepNext & 7;
#pragma unroll
                for (int i = 0; i < 4; ++i) {
                    const int slot = i * 256 + tid;
                    const int code = slot >> 2;
                    const int qq = (slot & 3) ^ ((code >> 1) & 3);
                    const unsigned short* src = whp + (nch * 256 + code) * 256 + ncs * 32 + qq * 8;
                    __builtin_amdgcn_global_load_lds((const AS1 void*)src,
                        (AS3 void*)((char*)&Bs[buf ^ 1][0] + slot * 16), 16, 0, 0);
                }
            }
            // compute from current buffer (hides staging latency)
            bf16x8 bh[4];
#pragma unroll
            for (int ct = 0; ct < 4; ++ct) {
                const int codeL = w * 64 + ct * 16 + nn;
                const int qp = q ^ ((codeL >> 1) & 3);
                bh[ct] = *(const bf16x8*)&Bs[buf][(codeL * 4 + qp) * 8];
            }
#pragma unroll
            for (int rt = 0; rt < 2; ++rt) {
                const int as = (cs * 4 + q) * 32 + rt * 16 + nn;
                const bf16x8 ah = *(const bf16x8*)&As[as * 8];
#pragma unroll
                for (int ct = 0; ct < 4; ++ct)
                    acc[rt][ct] = __builtin_amdgcn_mfma_f32_16x16x32_bf16(ah, bh[ct], acc[rt][ct], 0, 0, 0);
            }
            buf ^= 1;
            __syncthreads();   // vmcnt(0) drain: next buf staged; old-buf reads done
        }

        // ---- fold: approx d, shared row-max, candidate collection ----
        float wnv[4];
#pragma unroll
        for (int ct = 0; ct < 4; ++ct) wnv[ct] = wn[kb + w * 64 + ct * 16 + nn];
        float d[2][4][4];
        float rmax[8];
#pragma unroll
        for (int r8 = 0; r8 < 8; ++r8) rmax[r8] = -3.0e38f;
#pragma unroll
        for (int rt = 0; rt < 2; ++rt)
#pragma unroll
            for (int ct = 0; ct < 4; ++ct)
#pragma unroll
                for (int rg = 0; rg < 4; ++rg) {
                    const float dv = __builtin_fmaf(2.0f, acc[rt][ct][rg], -wnv[ct]);
                    d[rt][ct][rg] = dv;
                    rmax[rt * 4 + rg] = fmaxf(rmax[rt * 4 + rg], dv);
                }
#pragma unroll
        for (int r8 = 0; r8 < 8; ++r8) {
            float m = rmax[r8];
            m = fmaxf(m, __shfl_xor(m, 1, 64));
            m = fmaxf(m, __shfl_xor(m, 2, 64));
            m = fmaxf(m, __shfl_xor(m, 4, 64));
            m = fmaxf(m, __shfl_xor(m, 8, 64));
            rmax[r8] = m;
        }
        if (nn == 0) {
#pragma unroll
            for (int rt = 0; rt < 2; ++rt)
#pragma unroll
                for (int rg = 0; rg < 4; ++rg)
                    atomicMax(&rowmaxU[rt * 16 + q * 4 + rg], monof(rmax[rt * 4 + rg]));
        }
        __syncthreads();
        float th[8];
#pragma unroll
        for (int rt = 0; rt < 2; ++rt)
#pragma unroll
            for (int rg = 0; rg < 4; ++rg)
                th[rt * 4 + rg] = unmonof(rowmaxU[rt * 16 + q * 4 + rg]) - MARGIN;
#pragma unroll
        for (int rt = 0; rt < 2; ++rt)
#pragma unroll
            for (int ct = 0; ct < 4; ++ct)
#pragma unroll
                for (int rg = 0; rg < 4; ++rg)
                    if (d[rt][ct][rg] >= th[rt * 4 + rg]) {
                        const int row = rt * 16 + q * 4 + rg;
                        const int pos = atomicAdd(&ccnt[row], 1);
                        if (pos < CAP) ck[row][pos] = (unsigned short)(kb + w * 64 + ct * 16 + nn);
                    }
        // next step's trailing __syncthreads orders collection vs restage
    }
    __syncthreads();
    if (tid < 32) candc[rowBase + tid] = ccnt[tid];
#pragma unroll
    for (int i = 0; i < 8; ++i) {
        const int e = i * 256 + tid;    // 2048 entries = 32 rows x CAP(64)
        candk[(rowBase + (e >> 6)) * CAP + (e & 63)] = ck[e >> 6][e & 63];
    }
}

// ---------- K3: exact rescore — 256-thr blocks, wave per 4 rows, coalesced ----
__global__ __launch_bounds__(256) void k3_rescore(
    const float* __restrict__ xt, const float* __restrict__ weight,
    const float* __restrict__ wn, const float* __restrict__ ns1,
    const unsigned short* __restrict__ candk, const int* __restrict__ candc,
    int* __restrict__ idx)
{
    const int w = threadIdx.x >> 6, lane = threadIdx.x & 63;
    const int waveId = blockIdx.x * 4 + w;        // 0..4095
#pragma unroll
    for (int rr = 0; rr < 4; ++rr) {
        const int n = waveId * 4 + rr;
        const float4 xv = ((const float4*)(xt + n * 256))[lane];
        const int cnt = candc[n];
        const float nsv = ns1[n];
        float bestd = -3.0e38f; int bestk = 0x7fffffff;
        if (cnt <= CAP) {
            for (int i = 0; i < cnt; ++i) {
                const int k = candk[n * CAP + i];
                const float4 wv = ((const float4*)(weight + k * 256))[lane];
                float p = __fmul_rn(xv.x, wv.x);
                p = __builtin_fmaf(xv.y, wv.y, p);
                p = __builtin_fmaf(xv.z, wv.z, p);
                p = __builtin_fmaf(xv.w, wv.w, p);
#pragma unroll
                for (int off = 1; off < 64; off <<= 1) p += __shfl_xor(p, off, 64);
                const float t1 = __fadd_rn(nsv, -wn[k]);
                const float dd = __fadd_rn(t1, __fmul_rn(2.0f, p));
                if (dd > bestd || (dd == bestd && k < bestk)) { bestd = dd; bestk = k; }
            }
        } else {              // overflow fallback: exact full scan, wave-coalesced
            for (int k = 0; k < KCODES; ++k) {
                const float4 wv = ((const float4*)(weight + k * 256))[lane];
                float p = __fmul_rn(xv.x, wv.x);
                p = __builtin_fmaf(xv.y, wv.y, p);
                p = __builtin_fmaf(xv.z, wv.z, p);
                p = __builtin_fmaf(xv.w, wv.w, p);
#pragma unroll
                for (int off = 1; off < 64; off <<= 1) p += __shfl_xor(p, off, 64);
                const float t1 = __fadd_rn(nsv, -wn[k]);
                const float dd = __fadd_rn(t1, __fmul_rn(2.0f, p));
                if (dd > bestd) { bestd = dd; bestk = k; }   // ascending k: first-wins
            }
        }
        if (lane == 0) idx[n] = bestk;
    }
}

// ---------- K5: gather + transpose-tile coalesced store + loss partials -------
// grid (32 p-tiles, 8 c-tiles, 16 b), block (32,8). No global atomics:
// per-block {mask,err} partials go to part[bid][2]; k6 tree-reduces.
__global__ void k5_out(const float* __restrict__ xt, const float* __restrict__ weight,
                       const float* __restrict__ mask, const int* __restrict__ idx,
                       float* __restrict__ out, float* __restrict__ part)
{
    __shared__ float t[32][33];
    __shared__ float red[4][2];
    const int p0 = blockIdx.x * 32, c0 = blockIdx.y * 32, b = blockIdx.z;
    const int tx = threadIdx.x, ty = threadIdx.y;
    float vloc = 0.f, mloc = 0.f;
#pragma unroll
    for (int i = 0; i < 4; ++i) {
        const int pl = ty + i * 8;
        const int n = b * 1024 + p0 + pl;
        const int id = idx[n];
        const float wq = weight[id * 256 + c0 + tx];      // coalesced 128B per row
        const float xv = xt[n * 256 + c0 + tx];           // coalesced
        const float mval = mask[b * 1024 + p0 + pl];      // broadcast
        t[tx][pl] = wq;                                   // t[c-local][p-local]
        const float e = wq - xv;
        vloc += mval * e * e;
        if (blockIdx.y == 0 && tx == 0) {
            mloc += mval;
            out[OUT_IND + n] = (float)id;
        }
    }
    __syncthreads();
#pragma unroll
    for (int i = 0; i < 4; ++i) {
        const int cl = ty + i * 8;
        out[(b * 256 + c0 + cl) * 1024 + p0 + tx] = t[cl][tx];   // coalesced in tx
    }
    const int lin = ty * 32 + tx, lane = lin & 63, w = lin >> 6;
#pragma unroll
    for (int o = 32; o > 0; o >>= 1) {
        vloc += __shfl_down(vloc, o, 64);
        mloc += __shfl_down(mloc, o, 64);
    }
    if (lane == 0) { red[w][0] = mloc; red[w][1] = vloc; }
    __syncthreads();
    if (lin == 0) {
        const int bid = (b * 8 + blockIdx.y) * 32 + blockIdx.x;
        part[bid * 2 + 0] = red[0][0] + red[1][0] + red[2][0] + red[3][0];
        part[bid * 2 + 1] = red[0][1] + red[1][1] + red[2][1] + red[3][1];
    }
}

// ---------- K6: deterministic tree-reduce of 4096 partials + finalize loss ----
__global__ void k6_final(const float* __restrict__ part, float* __restrict__ out)
{
    __shared__ double red[4][2];
    const int tid = threadIdx.x;
    double m = 0.0, s = 0.0;
    for (int i = tid; i < 4096; i += 256) {
        m += (double)part[i * 2 + 0];
        s += (double)part[i * 2 + 1];
    }
    const int lane = tid & 63, w = tid >> 6;
    for (int o = 32; o > 0; o >>= 1) {
        m += __shfl_down(m, o, 64);
        s += __shfl_down(s, o, 64);
    }
    if (lane == 0) { red[w][0] = m; red[w][1] = s; }
    __syncthreads();
    if (tid == 0) {
        const double mt = red[0][0] + red[1][0] + red[2][0] + red[3][0];
        const double st = red[0][1] + red[1][1] + red[2][1] + red[3][1];
        out[OUT_LOSS] = (float)(1.25 * st / (256.0 * mt));
    }
}

extern "C" void kernel_launch(void* const* d_in, const int* in_sizes, int n_in,
                              void* d_out, int out_size, void* d_ws, size_t ws_size,
                              hipStream_t stream)
{
    const float* x      = (const float*)d_in[0];   // [16,256,32,32]
    const float* mask   = (const float*)d_in[1];   // [16,1,32,32]
    const float* weight = (const float*)d_in[2];   // [16384,256]
    float* out = (float*)d_out;
    float* ws  = (float*)d_ws;

    float* xt  = ws + OFF_XT;
    unsigned short* xhp = (unsigned short*)(ws + OFF_XHP);
    unsigned short* whp = (unsigned short*)(ws + OFF_WHP);
    float* wn   = ws + OFF_WN;
    float* ns1  = ws + OFF_NS1;
    int*   idx  = (int*)(ws + OFF_IDX);
    unsigned short* candk = (unsigned short*)(ws + OFF_CAND);
    int*   candc = (int*)(ws + OFF_CCNT);
    float* part = ws + OFF_PART;

    k1a_pack_x<<<dim3(32, 8, 16), dim3(32, 8), 0, stream>>>(x, xt, xhp);
    k_rownorm<<<512, 256, 0, stream>>>((const float4*)xt, ns1, -1.0f, nullptr);
    k_rownorm<<<512, 256, 0, stream>>>((const float4*)weight, wn, 1.0f, (ushort4*)whp);
    k2_mfma<<<512, 256, 0, stream>>>(xhp, whp, wn, candk, candc);
    k3_rescore<<<1024, 256, 0, stream>>>(xt, weight, wn, ns1, candk, candc, idx);
    k5_out<<<dim3(32, 8, 16), dim3(32, 8), 0, stream>>>(xt, weight, mask, idx, out, part);
    k6_final<<<1, 256, 0, stream>>>(part, out);
}

// Round 2
// 411.845 us; speedup vs baseline: 2.8960x; 1.2506x over previous
//
#include <hip/hip_runtime.h>

// Problem: B,C,H,W = 16,256,32,32; K=16384. N = 16384 rows.
// R12: k2 is LLC-BW bound (R0: 8.6GB/727us = 11.8 TB/s; R1: 4.3GB/395us = 10.9 TB/s
//      -- same ~11 TB/s sustained from Infinity Cache, since the 8MB codebook
//      can't fit a 4MB XCD L2). Fix: 64-row tiles x K-split-2 (traffic /2 -> 2.15GB),
//      with XCD-half affinity (half = bid&1, XCD = bid%8 round-robin) so each XCD's
//      L2 only sees one 4MB codebook half -> L2 can serve repeats. Sync schedule is
//      byte-identical to the proven R1 issue-early/1-barrier pipeline; only tile
//      geometry changed. Candidates are now per-(row, K-half), merged in k3.
#define KCODES 16384
#define NPOS   16384
#define KHALF  8192
#define CAPH   64      // per-half candidate cap (R10: 4 rows overflowed at 16; 64/half is ~P(0))
#define MARGIN 1e-4f   // ~100x the single-plane bf16 dot error (sigma ~1e-6 on d)

// ws float offsets (all within the 52.7MB footprint proven in R0)
#define OFF_XT    0           // [N][256] fp32 packed x ("flat")
#define OFF_XHP   4194304     // bf16 plane xh [N][256]
#define OFF_PART  6291456     // [4096][2] k5 per-block {mask,err} partials
#define OFF_CAND  6815744     // u16 [N][2][CAPH] candidate codes (1M floats, old XLP gap)
#define OFF_WHP   8388608     // bf16 plane wh [K][256]
#define OFF_WN    12582912    // [K]  |w|^2 (np-pairwise exact)
#define OFF_NS1   12599296    // [N] -|f|^2
#define OFF_IDX   12615680    // [N] final argmax (int)
#define OFF_CCNT  12632064    // int [N][2] candidate counts

#define OUT_LOSS  4194304
#define OUT_IND   4194305

#define AS1 __attribute__((address_space(1)))
#define AS3 __attribute__((address_space(3)))

typedef short bf16x8 __attribute__((ext_vector_type(8)));   // 8 bf16 = 4 VGPRs
typedef float f32x4  __attribute__((ext_vector_type(4)));

__device__ inline unsigned short bf16rn(float f) {
    unsigned u = __float_as_uint(f);
    return (unsigned short)((u + 0x7FFFu + ((u >> 16) & 1u)) >> 16);
}
__device__ inline float bf2f(unsigned short h) {
    return __uint_as_float(((unsigned)h) << 16);
}
__device__ inline unsigned monof(float f) {   // monotone float->uint key
    unsigned u = __float_as_uint(f);
    return (u & 0x80000000u) ? ~u : (u | 0x80000000u);
}
__device__ inline float unmonof(unsigned k) {
    unsigned u = (k & 0x80000000u) ? (k & 0x7fffffffu) : ~k;
    return __uint_as_float(u);
}

// ---------- K1a: pack x (B,C,HW) -> xt[N][256] fp32 + xh bf16, LDS transpose ----
__global__ void k1a_pack_x(const float* __restrict__ x, float* __restrict__ xt,
                           unsigned short* __restrict__ xhp)
{
    __shared__ float t[32][33];
    const int p0 = blockIdx.x * 32, c0 = blockIdx.y * 32, b = blockIdx.z;
    const int tx = threadIdx.x, ty = threadIdx.y;   // 32 x 8
#pragma unroll
    for (int i = 0; i < 4; ++i) {
        int cl = ty + i * 8;
        t[cl][tx] = x[(b * 256 + c0 + cl) * 1024 + p0 + tx];
    }
    __syncthreads();
#pragma unroll
    for (int i = 0; i < 4; ++i) {
        int pl = ty + i * 8;
        float v = t[tx][pl];
        int o = (b * 1024 + p0 + pl) * 256 + c0 + tx;
        xt[o] = v;
        xhp[o] = bf16rn(v);
    }
}

// ---------- Krn: numpy-pairwise fp32 sum of squares per 256-elem row ----------
__global__ void k_rownorm(const float4* __restrict__ src4, float* __restrict__ out,
                          float sign, ushort4* __restrict__ hp)
{
    __shared__ float4 rows[32 * 64];
    const int tid = threadIdx.x;
    const int r0 = blockIdx.x * 32;
#pragma unroll
    for (int i = 0; i < 8; ++i) {
        const float4 v = src4[r0 * 64 + tid + 256 * i];
        rows[tid + 256 * i] = v;
        if (hp) {
            ushort4 h;
            h.x = bf16rn(v.x); h.y = bf16rn(v.y);
            h.z = bf16rn(v.z); h.w = bf16rn(v.w);
            hp[r0 * 64 + tid + 256 * i] = h;
        }
    }
    __syncthreads();
    const int rl = tid >> 3, j = tid & 7;
    const float* qp = (const float*)&rows[rl * 64];
    float h[2];
#pragma unroll
    for (int half = 0; half < 2; ++half) {
        const float* p = qp + half * 128;
        float x = p[j];
        float r = __fmul_rn(x, x);
#pragma unroll
        for (int i = 1; i < 16; ++i) {
            float y = p[8 * i + j];
            r = __fadd_rn(r, __fmul_rn(y, y));
        }
        float t = __fadd_rn(r, __shfl_xor(r, 1));
        t = __fadd_rn(t, __shfl_xor(t, 2));
        t = __fadd_rn(t, __shfl_xor(t, 4));
        h[half] = t;
    }
    if (j == 0) out[r0 + rl] = sign * __fadd_rn(h[0], h[1]);
}

// ---------- K2: 64-row x K-half bf16 MFMA + approx-d candidate collection -----
// d_approx = 2*(xh.wh) - |w|^2 (per-row -|f|^2 constant omitted: argmax-invariant).
// Block = (rowGroup = bid>>1) x (K-half = bid&1). XCD = bid%8 -> each XCD L2
// only touches one 4MB codebook half.
__global__ __launch_bounds__(256, 2) void k2_mfma(
    const unsigned short* __restrict__ xhp, const unsigned short* __restrict__ whp,
    const float* __restrict__ wn,
    unsigned short* __restrict__ candk, int* __restrict__ candc)
{
    __shared__ __align__(16) unsigned short As[16384];     // 32KB: slot16 = cc*64 + row
    __shared__ __align__(16) unsigned short Bs[2][8192];   // 2x16KB: slot16 = code*4 + q'
    __shared__ unsigned rowmaxU[64];
    __shared__ int ccnt[64];
    __shared__ unsigned short ck[64][CAPH];                // 8 KB

    const int tid  = threadIdx.x;
    const int lane = tid & 63;
    const int w    = tid >> 6;     // wave 0..3 -> code sub-range
    const int q    = lane >> 4;    // k-chunk quad
    const int nn   = lane & 15;    // A-row / B-col / D-col position
    const int half = blockIdx.x & 1;
    const int rowBase = (blockIdx.x >> 1) * 64;
    const unsigned short* whpH = whp + half * (KHALF * 256);
    const float* wnH = wn + half * KHALF;

    // stage A once: 2048 slots of 16B (64 rows x 256 ch bf16)
#pragma unroll
    for (int i = 0; i < 8; ++i) {
        const int slot = i * 256 + tid;
        const int cc = slot >> 6, row = slot & 63;
        const unsigned short* src = xhp + (rowBase + row) * 256 + cc * 8;
        __builtin_amdgcn_global_load_lds((const AS1 void*)src,
                                         (AS3 void*)((char*)&As[0] + slot * 16), 16, 0, 0);
    }
    // stage B buf0 for step 0 (ch=0, cs=0)
#pragma unroll
    for (int i = 0; i < 4; ++i) {
        const int slot = i * 256 + tid;
        const int code = slot >> 2;
        const int qq = (slot & 3) ^ ((code >> 1) & 3);     // bank swizzle
        const unsigned short* src = whpH + code * 256 + qq * 8;
        __builtin_amdgcn_global_load_lds((const AS1 void*)src,
            (AS3 void*)((char*)&Bs[0][0] + slot * 16), 16, 0, 0);
    }
    if (tid < 64) { rowmaxU[tid] = 0u; ccnt[tid] = 0; }
    __syncthreads();           // drains vmcnt: As + Bs[0] ready

    int buf = 0;
    for (int ch = 0; ch < 32; ++ch) {
        const int kb = ch * 256;
        f32x4 acc[4][4];
#pragma unroll
        for (int rt = 0; rt < 4; ++rt)
#pragma unroll
            for (int ct = 0; ct < 4; ++ct) acc[rt][ct] = (f32x4){0.f, 0.f, 0.f, 0.f};

        for (int cs = 0; cs < 8; ++cs) {
            // issue next step's staging into the other buffer (issue-early)
            const int stepNext = ch * 8 + cs + 1;
            if (stepNext < 256) {
                const int nch = stepNext >> 3, ncs = stepNext & 7;
#pragma unroll
                for (int i = 0; i < 4; ++i) {
                    const int slot = i * 256 + tid;
                    const int code = slot >> 2;
                    const int qq = (slot & 3) ^ ((code >> 1) & 3);
                    const unsigned short* src = whpH + (nch * 256 + code) * 256 + ncs * 32 + qq * 8;
                    __builtin_amdgcn_global_load_lds((const AS1 void*)src,
                        (AS3 void*)((char*)&Bs[buf ^ 1][0] + slot * 16), 16, 0, 0);
                }
            }
            // compute from current buffer (hides staging latency)
            bf16x8 bh[4];
#pragma unroll
            for (int ct = 0; ct < 4; ++ct) {
                const int codeL = w * 64 + ct * 16 + nn;
                const int qp = q ^ ((codeL >> 1) & 3);
                bh[ct] = *(const bf16x8*)&Bs[buf][(codeL * 4 + qp) * 8];
            }
#pragma unroll
            for (int rt = 0; rt < 4; ++rt) {
                const int as = (cs * 4 + q) * 64 + rt * 16 + nn;
                const bf16x8 ah = *(const bf16x8*)&As[as * 8];
#pragma unroll
                for (int ct = 0; ct < 4; ++ct)
                    acc[rt][ct] = __builtin_amdgcn_mfma_f32_16x16x32_bf16(ah, bh[ct], acc[rt][ct], 0, 0, 0);
            }
            buf ^= 1;
            __syncthreads();   // vmcnt(0) drain: next buf staged; old-buf reads done
        }

        // ---- fold: approx d, shared row-max, candidate collection ----
        float wnv[4];
#pragma unroll
        for (int ct = 0; ct < 4; ++ct) wnv[ct] = wnH[kb + w * 64 + ct * 16 + nn];
        float rmax[16];
#pragma unroll
        for (int r16 = 0; r16 < 16; ++r16) rmax[r16] = -3.0e38f;
#pragma unroll
        for (int rt = 0; rt < 4; ++rt)
#pragma unroll
            for (int ct = 0; ct < 4; ++ct)
#pragma unroll
                for (int rg = 0; rg < 4; ++rg) {
                    const float dv = __builtin_fmaf(2.0f, acc[rt][ct][rg], -wnv[ct]);
                    rmax[rt * 4 + rg] = fmaxf(rmax[rt * 4 + rg], dv);
                }
#pragma unroll
        for (int r16 = 0; r16 < 16; ++r16) {
            float m = rmax[r16];
            m = fmaxf(m, __shfl_xor(m, 1, 64));
            m = fmaxf(m, __shfl_xor(m, 2, 64));
            m = fmaxf(m, __shfl_xor(m, 4, 64));
            m = fmaxf(m, __shfl_xor(m, 8, 64));
            rmax[r16] = m;
        }
        if (nn == 0) {
#pragma unroll
            for (int rt = 0; rt < 4; ++rt)
#pragma unroll
                for (int rg = 0; rg < 4; ++rg)
                    atomicMax(&rowmaxU[rt * 16 + q * 4 + rg], monof(rmax[rt * 4 + rg]));
        }
        __syncthreads();
        float th[16];
#pragma unroll
        for (int rt = 0; rt < 4; ++rt)
#pragma unroll
            for (int rg = 0; rg < 4; ++rg)
                th[rt * 4 + rg] = unmonof(rowmaxU[rt * 16 + q * 4 + rg]) - MARGIN;
#pragma unroll
        for (int rt = 0; rt < 4; ++rt)
#pragma unroll
            for (int ct = 0; ct < 4; ++ct)
#pragma unroll
                for (int rg = 0; rg < 4; ++rg) {
                    const float dv = __builtin_fmaf(2.0f, acc[rt][ct][rg], -wnv[ct]);
                    if (dv >= th[rt * 4 + rg]) {
                        const int row = rt * 16 + q * 4 + rg;
                        const int pos = atomicAdd(&ccnt[row], 1);
                        if (pos < CAPH)
                            ck[row][pos] = (unsigned short)(half * KHALF + kb + w * 64 + ct * 16 + nn);
                    }
                }
        // next step's trailing __syncthreads orders collection vs restage
    }
    __syncthreads();
    if (tid < 64) candc[(rowBase + tid) * 2 + half] = ccnt[tid];
#pragma unroll
    for (int i = 0; i < 16; ++i) {
        const int e = i * 256 + tid;    // 4096 entries = 64 rows x CAPH(64)
        candk[((rowBase + (e >> 6)) * 2 + half) * CAPH + (e & 63)] = ck[e >> 6][e & 63];
    }
}

// ---------- K3: exact rescore — merge both K-halves' candidate lists ----------
__global__ __launch_bounds__(256) void k3_rescore(
    const float* __restrict__ xt, const float* __restrict__ weight,
    const float* __restrict__ wn, const float* __restrict__ ns1,
    const unsigned short* __restrict__ candk, const int* __restrict__ candc,
    int* __restrict__ idx)
{
    const int w = threadIdx.x >> 6, lane = threadIdx.x & 63;
    const int waveId = blockIdx.x * 4 + w;        // 0..4095
#pragma unroll
    for (int rr = 0; rr < 4; ++rr) {
        const int n = waveId * 4 + rr;
        const float4 xv = ((const float4*)(xt + n * 256))[lane];
        const float nsv = ns1[n];
        float bestd = -3.0e38f; int bestk = 0x7fffffff;
#pragma unroll
        for (int half = 0; half < 2; ++half) {
            const int cnt = candc[n * 2 + half];
            if (cnt <= CAPH) {
                for (int i = 0; i < cnt; ++i) {
                    const int k = candk[(n * 2 + half) * CAPH + i];
                    const float4 wv = ((const float4*)(weight + k * 256))[lane];
                    float p = __fmul_rn(xv.x, wv.x);
                    p = __builtin_fmaf(xv.y, wv.y, p);
                    p = __builtin_fmaf(xv.z, wv.z, p);
                    p = __builtin_fmaf(xv.w, wv.w, p);
#pragma unroll
                    for (int off = 1; off < 64; off <<= 1) p += __shfl_xor(p, off, 64);
                    const float t1 = __fadd_rn(nsv, -wn[k]);
                    const float dd = __fadd_rn(t1, __fmul_rn(2.0f, p));
                    if (dd > bestd || (dd == bestd && k < bestk)) { bestd = dd; bestk = k; }
                }
            } else {          // overflow fallback: exact scan of this half
                for (int k = half * KHALF; k < (half + 1) * KHALF; ++k) {
                    const float4 wv = ((const float4*)(weight + k * 256))[lane];
                    float p = __fmul_rn(xv.x, wv.x);
                    p = __builtin_fmaf(xv.y, wv.y, p);
                    p = __builtin_fmaf(xv.z, wv.z, p);
                    p = __builtin_fmaf(xv.w, wv.w, p);
#pragma unroll
                    for (int off = 1; off < 64; off <<= 1) p += __shfl_xor(p, off, 64);
                    const float t1 = __fadd_rn(nsv, -wn[k]);
                    const float dd = __fadd_rn(t1, __fmul_rn(2.0f, p));
                    if (dd > bestd || (dd == bestd && k < bestk)) { bestd = dd; bestk = k; }
                }
            }
        }
        if (lane == 0) idx[n] = bestk;
    }
}

// ---------- K5: gather + transpose-tile coalesced store + loss partials -------
__global__ void k5_out(const float* __restrict__ xt, const float* __restrict__ weight,
                       const float* __restrict__ mask, const int* __restrict__ idx,
                       float* __restrict__ out, float* __restrict__ part)
{
    __shared__ float t[32][33];
    __shared__ float red[4][2];
    const int p0 = blockIdx.x * 32, c0 = blockIdx.y * 32, b = blockIdx.z;
    const int tx = threadIdx.x, ty = threadIdx.y;
    float vloc = 0.f, mloc = 0.f;
#pragma unroll
    for (int i = 0; i < 4; ++i) {
        const int pl = ty + i * 8;
        const int n = b * 1024 + p0 + pl;
        const int id = idx[n];
        const float wq = weight[id * 256 + c0 + tx];      // coalesced 128B per row
        const float xv = xt[n * 256 + c0 + tx];           // coalesced
        const float mval = mask[b * 1024 + p0 + pl];      // broadcast
        t[tx][pl] = wq;                                   // t[c-local][p-local]
        const float e = wq - xv;
        vloc += mval * e * e;
        if (blockIdx.y == 0 && tx == 0) {
            mloc += mval;
            out[OUT_IND + n] = (float)id;
        }
    }
    __syncthreads();
#pragma unroll
    for (int i = 0; i < 4; ++i) {
        const int cl = ty + i * 8;
        out[(b * 256 + c0 + cl) * 1024 + p0 + tx] = t[cl][tx];   // coalesced in tx
    }
    const int lin = ty * 32 + tx, lane = lin & 63, w = lin >> 6;
#pragma unroll
    for (int o = 32; o > 0; o >>= 1) {
        vloc += __shfl_down(vloc, o, 64);
        mloc += __shfl_down(mloc, o, 64);
    }
    if (lane == 0) { red[w][0] = mloc; red[w][1] = vloc; }
    __syncthreads();
    if (lin == 0) {
        const int bid = (b * 8 + blockIdx.y) * 32 + blockIdx.x;
        part[bid * 2 + 0] = red[0][0] + red[1][0] + red[2][0] + red[3][0];
        part[bid * 2 + 1] = red[0][1] + red[1][1] + red[2][1] + red[3][1];
    }
}

// ---------- K6: deterministic tree-reduce of 4096 partials + finalize loss ----
__global__ void k6_final(const float* __restrict__ part, float* __restrict__ out)
{
    __shared__ double red[4][2];
    const int tid = threadIdx.x;
    double m = 0.0, s = 0.0;
    for (int i = tid; i < 4096; i += 256) {
        m += (double)part[i * 2 + 0];
        s += (double)part[i * 2 + 1];
    }
    const int lane = tid & 63, w = tid >> 6;
    for (int o = 32; o > 0; o >>= 1) {
        m += __shfl_down(m, o, 64);
        s += __shfl_down(s, o, 64);
    }
    if (lane == 0) { red[w][0] = m; red[w][1] = s; }
    __syncthreads();
    if (tid == 0) {
        const double mt = red[0][0] + red[1][0] + red[2][0] + red[3][0];
        const double st = red[0][1] + red[1][1] + red[2][1] + red[3][1];
        out[OUT_LOSS] = (float)(1.25 * st / (256.0 * mt));
    }
}

extern "C" void kernel_launch(void* const* d_in, const int* in_sizes, int n_in,
                              void* d_out, int out_size, void* d_ws, size_t ws_size,
                              hipStream_t stream)
{
    const float* x      = (const float*)d_in[0];   // [16,256,32,32]
    const float* mask   = (const float*)d_in[1];   // [16,1,32,32]
    const float* weight = (const float*)d_in[2];   // [16384,256]
    float* out = (float*)d_out;
    float* ws  = (float*)d_ws;

    float* xt  = ws + OFF_XT;
    unsigned short* xhp = (unsigned short*)(ws + OFF_XHP);
    unsigned short* whp = (unsigned short*)(ws + OFF_WHP);
    float* wn   = ws + OFF_WN;
    float* ns1  = ws + OFF_NS1;
    int*   idx  = (int*)(ws + OFF_IDX);
    unsigned short* candk = (unsigned short*)(ws + OFF_CAND);
    int*   candc = (int*)(ws + OFF_CCNT);
    float* part = ws + OFF_PART;

    k1a_pack_x<<<dim3(32, 8, 16), dim3(32, 8), 0, stream>>>(x, xt, xhp);
    k_rownorm<<<512, 256, 0, stream>>>((const float4*)xt, ns1, -1.0f, nullptr);
    k_rownorm<<<512, 256, 0, stream>>>((const float4*)weight, wn, 1.0f, (ushort4*)whp);
    k2_mfma<<<512, 256, 0, stream>>>(xhp, whp, wn, candk, candc);
    k3_rescore<<<1024, 256, 0, stream>>>(xt, weight, wn, ns1, candk, candc, idx);
    k5_out<<<dim3(32, 8, 16), dim3(32, 8), 0, stream>>>(xt, weight, mask, idx, out, part);
    k6_final<<<1, 256, 0, stream>>>(part, out);
}